// Round 1
// baseline (1306.524 us; speedup 1.0000x reference)
//
#include <hip/hip_runtime.h>

#define NG 16   // num_graphs (fixed by problem)
#define D 64    // feature width at every aggregation point

// ---------------------------------------------------------------------------
// Scatter-aggregate: agg[dst] += feat[src] for valid edges.
// 16 threads per edge, each handles 4 contiguous features via float4 gather
// + 4 global fp32 atomics. Valid mask computed on the fly:
//   g = e / per,  thr = g * (N/NG),  valid = (src >= thr && dst >= thr)
// ---------------------------------------------------------------------------
__global__ void scatter_agg_kernel(const float* __restrict__ feat,
                                   const int* __restrict__ ei,
                                   float* __restrict__ agg,
                                   int E, int per, int tmul, int total) {
  int stride = gridDim.x * blockDim.x;
  for (int t = blockIdx.x * blockDim.x + threadIdx.x; t < total; t += stride) {
    int e = t >> 4;
    int q = t & 15;
    int src = ei[e];
    int dst = ei[E + e];
    int g = e / per;              // compiler magic-div
    int thr = g * tmul;
    if (src >= thr && dst >= thr) {
      const float4 v = *(const float4*)(feat + (size_t)src * D + q * 4);
      float* base = agg + (size_t)dst * D + q * 4;
      atomicAdd(base + 0, v.x);
      atomicAdd(base + 1, v.y);
      atomicAdd(base + 2, v.z);
      atomicAdd(base + 3, v.w);
    }
  }
}

// ---------------------------------------------------------------------------
// Fused GIN-node update: out = relu( relu((A+B) @ Wa + ba) @ Wb + bb )
// Thread-per-row. Weight reads are wave-uniform -> compiler scalarizes to
// s_load; row data via float4.
// ---------------------------------------------------------------------------
template <int MID>
__global__ __launch_bounds__(256) void mlp_kernel(
    const float* __restrict__ A, const float* __restrict__ Bg,
    const float* __restrict__ Wa, const float* __restrict__ ba,
    const float* __restrict__ Wb, const float* __restrict__ bb,
    float* __restrict__ out, int N) {
  int row = blockIdx.x * 256 + threadIdx.x;
  if (row >= N) return;

  const float4* a4 = (const float4*)(A + (size_t)row * D);
  const float4* b4 = (const float4*)(Bg + (size_t)row * D);
  float in[D];
#pragma unroll
  for (int q = 0; q < D / 4; q++) {
    float4 av = a4[q];
    float4 bv = b4[q];
    in[4 * q + 0] = av.x + bv.x;
    in[4 * q + 1] = av.y + bv.y;
    in[4 * q + 2] = av.z + bv.z;
    in[4 * q + 3] = av.w + bv.w;
  }

  float mid[MID];
#pragma unroll 4
  for (int k = 0; k < MID; k++) {
    float acc = ba[k];
#pragma unroll
    for (int j = 0; j < D; j++) acc += in[j] * Wa[j * MID + k];
    mid[k] = fmaxf(acc, 0.f);
  }

  float4* o4 = (float4*)(out + (size_t)row * D);
#pragma unroll 2
  for (int c0 = 0; c0 < D; c0 += 4) {
    float acc0 = bb[c0 + 0];
    float acc1 = bb[c0 + 1];
    float acc2 = bb[c0 + 2];
    float acc3 = bb[c0 + 3];
#pragma unroll
    for (int k = 0; k < MID; k++) {
      float m = mid[k];
      acc0 += m * Wb[k * D + c0 + 0];
      acc1 += m * Wb[k * D + c0 + 1];
      acc2 += m * Wb[k * D + c0 + 2];
      acc3 += m * Wb[k * D + c0 + 3];
    }
    o4[c0 >> 2] = make_float4(fmaxf(acc0, 0.f), fmaxf(acc1, 0.f),
                              fmaxf(acc2, 0.f), fmaxf(acc3, 0.f));
  }
}

// ---------------------------------------------------------------------------
// Column sums + sum-of-squares for BN training stats.
// lane -> column (coalesced), register accumulation, LDS cross-wave reduce,
// one global atomic per column per block.
// ---------------------------------------------------------------------------
__global__ void stats_kernel(const float* __restrict__ h, int N,
                             float* __restrict__ sum, float* __restrict__ sumsq) {
  __shared__ float ls[4 * D];
  __shared__ float lq[4 * D];
  int tid = threadIdx.x;
  int c = tid & (D - 1), w = tid >> 6;
  int chunk = (N + gridDim.x - 1) / gridDim.x;
  int r0 = blockIdx.x * chunk;
  int r1 = min(N, r0 + chunk);
  float s = 0.f, q = 0.f;
  for (int r = r0 + w; r < r1; r += 4) {
    float v = h[(size_t)r * D + c];
    s += v;
    q += v * v;
  }
  ls[w * D + c] = s;
  lq[w * D + c] = q;
  __syncthreads();
  if (tid < D) {
    float ts = ls[c] + ls[D + c] + ls[2 * D + c] + ls[3 * D + c];
    float tq = lq[c] + lq[D + c] + lq[2 * D + c] + lq[3 * D + c];
    atomicAdd(&sum[c], ts);
    atomicAdd(&sumsq[c], tq);
  }
}

// a = gamma * rsqrt(var + eps); b = beta - mean * a
__global__ void coeff_kernel(const float* __restrict__ sum,
                             const float* __restrict__ sumsq,
                             const float* __restrict__ gamma,
                             const float* __restrict__ beta,
                             float invN, float* __restrict__ a,
                             float* __restrict__ b) {
  int c = threadIdx.x;
  if (c < D) {
    float mean = sum[c] * invN;
    float var = sumsq[c] * invN - mean * mean;
    float av = gamma[c] * rsqrtf(var + 1e-5f);
    a[c] = av;
    b[c] = beta[c] - mean * av;
  }
}

// In-place h = a[c]*h + b[c], float4-vectorized.
__global__ void bn_apply_kernel(float* __restrict__ h, const float* __restrict__ a,
                                const float* __restrict__ b, int total4) {
  int t = blockIdx.x * blockDim.x + threadIdx.x;
  if (t < total4) {
    float4 v = ((float4*)h)[t];
    int c0 = (t & 15) * 4;
    v.x = fmaf(v.x, a[c0 + 0], b[c0 + 0]);
    v.y = fmaf(v.y, a[c0 + 1], b[c0 + 1]);
    v.z = fmaf(v.z, a[c0 + 2], b[c0 + 2]);
    v.w = fmaf(v.w, a[c0 + 3], b[c0 + 3]);
    ((float4*)h)[t] = v;
  }
}

// ---------------------------------------------------------------------------
// Per-graph column sums + counts. Exploits sorted `batch`: per-thread
// run-length accumulation, flush with one atomic per run per column.
// ---------------------------------------------------------------------------
__global__ void pool_kernel(const float* __restrict__ h, const int* __restrict__ batch,
                            int N, float* __restrict__ pool, float* __restrict__ cnt) {
  int tid = threadIdx.x;
  int c = tid & (D - 1), w = tid >> 6;
  int chunk = (N + gridDim.x - 1) / gridDim.x;
  int r0 = blockIdx.x * chunk;
  int r1 = min(N, r0 + chunk);
  float acc = 0.f, lc = 0.f;
  int cur = -1;
  for (int r = r0 + w; r < r1; r += 4) {
    int g = batch[r];
    if (g != cur) {
      if (cur >= 0) {
        atomicAdd(&pool[cur * D + c], acc);
        if (c == 0) atomicAdd(&cnt[cur], lc);
      }
      cur = g;
      acc = 0.f;
      lc = 0.f;
    }
    acc += h[(size_t)r * D + c];
    lc += 1.f;
  }
  if (cur >= 0) {
    atomicAdd(&pool[cur * D + c], acc);
    if (c == 0) atomicAdd(&cnt[cur], lc);
  }
}

// out[g,c] = (a2[c]*pool[g,c] + cnt[g]*b2[c]) / max(cnt[g], 1)
// (BN2 affine commutes with the mean-pool since it's per-column linear)
__global__ void final_kernel(const float* __restrict__ pool,
                             const float* __restrict__ cnt,
                             const float* __restrict__ a,
                             const float* __restrict__ b,
                             float* __restrict__ out) {
  int t = blockIdx.x * blockDim.x + threadIdx.x;
  if (t < NG * D) {
    int g = t >> 6, c = t & (D - 1);
    float n = cnt[g];
    out[t] = (a[c] * pool[t] + n * b[c]) / fmaxf(n, 1.f);
  }
}

extern "C" void kernel_launch(void* const* d_in, const int* in_sizes, int n_in,
                              void* d_out, int out_size, void* d_ws, size_t ws_size,
                              hipStream_t stream) {
  const float* x   = (const float*)d_in[0];
  const int* ei    = (const int*)d_in[1];
  const int* batch = (const int*)d_in[2];
  // d_in[3]=num_graphs, d_in[4]=num_nodes (device scalars; derived from sizes instead)
  const float* W1a = (const float*)d_in[5];
  const float* b1a = (const float*)d_in[6];
  const float* W1b = (const float*)d_in[7];
  const float* b1b = (const float*)d_in[8];
  const float* g1  = (const float*)d_in[9];
  const float* be1 = (const float*)d_in[10];
  const float* W2a = (const float*)d_in[11];
  const float* b2a = (const float*)d_in[12];
  const float* W2b = (const float*)d_in[13];
  const float* b2b = (const float*)d_in[14];
  const float* g2  = (const float*)d_in[15];
  const float* be2 = (const float*)d_in[16];

  int N = in_sizes[0] / D;        // 100000
  int E = in_sizes[1] / 2;        // 1600000
  int per = E / NG;               // 100000
  int tmul = N / NG;              // 6250

  float* ws = (float*)d_ws;
  size_t nd = (size_t)N * D;
  float* agg   = ws;              // reused for both aggregations
  float* h1    = ws + nd;         // post-MLP1 (later BN'd in place)
  float* h2    = ws + 2 * nd;     // post-MLP2
  float* stats = ws + 3 * nd;
  float* sum1 = stats +   0; float* sq1 = stats +  64;
  float* a1   = stats + 128; float* b1  = stats + 192;
  float* sum2 = stats + 256; float* sq2 = stats + 320;
  float* a2   = stats + 384; float* b2  = stats + 448;
  float* pool = stats + 512;      // 16*64
  float* cnt  = stats + 512 + NG * D;  // 16

  hipMemsetAsync(agg, 0, nd * sizeof(float), stream);
  hipMemsetAsync(stats, 0, (512 + NG * D + NG) * sizeof(float), stream);

  int total = E * 16;
  dim3 sgrid(16384), sblk(256);
  scatter_agg_kernel<<<sgrid, sblk, 0, stream>>>(x, ei, agg, E, per, tmul, total);

  int mblocks = (N + 255) / 256;
  mlp_kernel<32><<<mblocks, 256, 0, stream>>>(x, agg, W1a, b1a, W1b, b1b, h1, N);
  stats_kernel<<<256, 256, 0, stream>>>(h1, N, sum1, sq1);
  coeff_kernel<<<1, 64, 0, stream>>>(sum1, sq1, g1, be1, 1.f / N, a1, b1);
  bn_apply_kernel<<<(N * 16 + 255) / 256, 256, 0, stream>>>(h1, a1, b1, N * 16);

  hipMemsetAsync(agg, 0, nd * sizeof(float), stream);
  scatter_agg_kernel<<<sgrid, sblk, 0, stream>>>(h1, ei, agg, E, per, tmul, total);
  mlp_kernel<64><<<mblocks, 256, 0, stream>>>(h1, agg, W2a, b2a, W2b, b2b, h2, N);
  stats_kernel<<<256, 256, 0, stream>>>(h2, N, sum2, sq2);
  coeff_kernel<<<1, 64, 0, stream>>>(sum2, sq2, g2, be2, 1.f / N, a2, b2);

  pool_kernel<<<256, 256, 0, stream>>>(h2, batch, N, pool, cnt);
  final_kernel<<<4, 256, 0, stream>>>(pool, cnt, a2, b2, (float*)d_out);
}

// Round 2
// 414.667 us; speedup vs baseline: 3.1508x; 3.1508x over previous
//
#include <hip/hip_runtime.h>

#define NG 16     // num_graphs (fixed by problem)
#define D 64      // feature width at every aggregation point
#define SLOT 64   // CSR slots per node; in-degree ~ Poisson(16), P(>=64) ~ 2e-18

// ---------------------------------------------------------------------------
// Build fixed-stride CSR by destination. One int atomic per VALID edge.
//   valid: g = e/per, thr = g*tmul, src >= thr && dst >= thr
// fill[] must be zeroed beforehand; doubles as per-node degree afterwards.
// ---------------------------------------------------------------------------
__global__ void build_csr_kernel(const int* __restrict__ ei,
                                 int* __restrict__ fill,
                                 int* __restrict__ col,
                                 int E, int per, int tmul) {
  int e = blockIdx.x * blockDim.x + threadIdx.x;
  if (e >= E) return;
  int src = ei[e];
  int dst = ei[E + e];
  int g = e / per;            // compiler magic-div
  int thr = g * tmul;
  if (src >= thr && dst >= thr) {
    int k = atomicAdd(&fill[dst], 1);
    if (k < SLOT) col[dst * SLOT + k] = src;   // clamp is paranoia-only
  }
}

// ---------------------------------------------------------------------------
// Pull-gather aggregation: agg[i] = sum_{j in N(i)} feat[j]. No atomics.
// 16 threads per node; lane q covers features [4q,4q+4). Each neighbor is a
// coalesced 256B wave read of feat[src].
// ---------------------------------------------------------------------------
__global__ __launch_bounds__(256) void gather_agg_kernel(
    const float* __restrict__ feat, const int* __restrict__ col,
    const int* __restrict__ deg, float* __restrict__ agg, int N) {
  int t = blockIdx.x * blockDim.x + threadIdx.x;
  int node = t >> 4;
  int q = t & 15;
  if (node >= N) return;
  int d = min(deg[node], SLOT);
  const int* cl = col + node * SLOT;
  float4 acc = make_float4(0.f, 0.f, 0.f, 0.f);
  for (int j = 0; j < d; j++) {
    int s = cl[j];
    const float4 v = *(const float4*)(feat + (size_t)s * D + q * 4);
    acc.x += v.x; acc.y += v.y; acc.z += v.z; acc.w += v.w;
  }
  *(float4*)(agg + (size_t)node * D + q * 4) = acc;
}

// ---------------------------------------------------------------------------
// Fused GIN-node update: out = relu( relu((A+B) @ Wa + ba) @ Wb + bb )
// Thread-per-row; wave-uniform weight reads scalarize to s_load.
// ---------------------------------------------------------------------------
template <int MID>
__global__ __launch_bounds__(256) void mlp_kernel(
    const float* __restrict__ A, const float* __restrict__ Bg,
    const float* __restrict__ Wa, const float* __restrict__ ba,
    const float* __restrict__ Wb, const float* __restrict__ bb,
    float* __restrict__ out, int N) {
  int row = blockIdx.x * 256 + threadIdx.x;
  if (row >= N) return;

  const float4* a4 = (const float4*)(A + (size_t)row * D);
  const float4* b4 = (const float4*)(Bg + (size_t)row * D);
  float in[D];
#pragma unroll
  for (int q = 0; q < D / 4; q++) {
    float4 av = a4[q];
    float4 bv = b4[q];
    in[4 * q + 0] = av.x + bv.x;
    in[4 * q + 1] = av.y + bv.y;
    in[4 * q + 2] = av.z + bv.z;
    in[4 * q + 3] = av.w + bv.w;
  }

  float mid[MID];
#pragma unroll 4
  for (int k = 0; k < MID; k++) {
    float acc = ba[k];
#pragma unroll
    for (int j = 0; j < D; j++) acc += in[j] * Wa[j * MID + k];
    mid[k] = fmaxf(acc, 0.f);
  }

  float4* o4 = (float4*)(out + (size_t)row * D);
#pragma unroll 2
  for (int c0 = 0; c0 < D; c0 += 4) {
    float acc0 = bb[c0 + 0];
    float acc1 = bb[c0 + 1];
    float acc2 = bb[c0 + 2];
    float acc3 = bb[c0 + 3];
#pragma unroll
    for (int k = 0; k < MID; k++) {
      float m = mid[k];
      acc0 += m * Wb[k * D + c0 + 0];
      acc1 += m * Wb[k * D + c0 + 1];
      acc2 += m * Wb[k * D + c0 + 2];
      acc3 += m * Wb[k * D + c0 + 3];
    }
    o4[c0 >> 2] = make_float4(fmaxf(acc0, 0.f), fmaxf(acc1, 0.f),
                              fmaxf(acc2, 0.f), fmaxf(acc3, 0.f));
  }
}

// ---------------------------------------------------------------------------
// Column sums + sum-of-squares for BN training stats.
// ---------------------------------------------------------------------------
__global__ void stats_kernel(const float* __restrict__ h, int N,
                             float* __restrict__ sum, float* __restrict__ sumsq) {
  __shared__ float ls[4 * D];
  __shared__ float lq[4 * D];
  int tid = threadIdx.x;
  int c = tid & (D - 1), w = tid >> 6;
  int chunk = (N + gridDim.x - 1) / gridDim.x;
  int r0 = blockIdx.x * chunk;
  int r1 = min(N, r0 + chunk);
  float s = 0.f, q = 0.f;
  for (int r = r0 + w; r < r1; r += 4) {
    float v = h[(size_t)r * D + c];
    s += v;
    q += v * v;
  }
  ls[w * D + c] = s;
  lq[w * D + c] = q;
  __syncthreads();
  if (tid < D) {
    float ts = ls[c] + ls[D + c] + ls[2 * D + c] + ls[3 * D + c];
    float tq = lq[c] + lq[D + c] + lq[2 * D + c] + lq[3 * D + c];
    atomicAdd(&sum[c], ts);
    atomicAdd(&sumsq[c], tq);
  }
}

// a = gamma * rsqrt(var + eps); b = beta - mean * a
__global__ void coeff_kernel(const float* __restrict__ sum,
                             const float* __restrict__ sumsq,
                             const float* __restrict__ gamma,
                             const float* __restrict__ beta,
                             float invN, float* __restrict__ a,
                             float* __restrict__ b) {
  int c = threadIdx.x;
  if (c < D) {
    float mean = sum[c] * invN;
    float var = sumsq[c] * invN - mean * mean;
    float av = gamma[c] * rsqrtf(var + 1e-5f);
    a[c] = av;
    b[c] = beta[c] - mean * av;
  }
}

// In-place h = a[c]*h + b[c], float4-vectorized.
__global__ void bn_apply_kernel(float* __restrict__ h, const float* __restrict__ a,
                                const float* __restrict__ b, int total4) {
  int t = blockIdx.x * blockDim.x + threadIdx.x;
  if (t < total4) {
    float4 v = ((float4*)h)[t];
    int c0 = (t & 15) * 4;
    v.x = fmaf(v.x, a[c0 + 0], b[c0 + 0]);
    v.y = fmaf(v.y, a[c0 + 1], b[c0 + 1]);
    v.z = fmaf(v.z, a[c0 + 2], b[c0 + 2]);
    v.w = fmaf(v.w, a[c0 + 3], b[c0 + 3]);
    ((float4*)h)[t] = v;
  }
}

// ---------------------------------------------------------------------------
// Per-graph column sums + counts (batch is sorted -> run-length flushes).
// ---------------------------------------------------------------------------
__global__ void pool_kernel(const float* __restrict__ h, const int* __restrict__ batch,
                            int N, float* __restrict__ pool, float* __restrict__ cnt) {
  int tid = threadIdx.x;
  int c = tid & (D - 1), w = tid >> 6;
  int chunk = (N + gridDim.x - 1) / gridDim.x;
  int r0 = blockIdx.x * chunk;
  int r1 = min(N, r0 + chunk);
  float acc = 0.f, lc = 0.f;
  int cur = -1;
  for (int r = r0 + w; r < r1; r += 4) {
    int g = batch[r];
    if (g != cur) {
      if (cur >= 0) {
        atomicAdd(&pool[cur * D + c], acc);
        if (c == 0) atomicAdd(&cnt[cur], lc);
      }
      cur = g;
      acc = 0.f;
      lc = 0.f;
    }
    acc += h[(size_t)r * D + c];
    lc += 1.f;
  }
  if (cur >= 0) {
    atomicAdd(&pool[cur * D + c], acc);
    if (c == 0) atomicAdd(&cnt[cur], lc);
  }
}

// out[g,c] = (a2[c]*pool[g,c] + cnt[g]*b2[c]) / max(cnt[g], 1)
__global__ void final_kernel(const float* __restrict__ pool,
                             const float* __restrict__ cnt,
                             const float* __restrict__ a,
                             const float* __restrict__ b,
                             float* __restrict__ out) {
  int t = blockIdx.x * blockDim.x + threadIdx.x;
  if (t < NG * D) {
    int g = t >> 6, c = t & (D - 1);
    float n = cnt[g];
    out[t] = (a[c] * pool[t] + n * b[c]) / fmaxf(n, 1.f);
  }
}

extern "C" void kernel_launch(void* const* d_in, const int* in_sizes, int n_in,
                              void* d_out, int out_size, void* d_ws, size_t ws_size,
                              hipStream_t stream) {
  const float* x   = (const float*)d_in[0];
  const int* ei    = (const int*)d_in[1];
  const int* batch = (const int*)d_in[2];
  const float* W1a = (const float*)d_in[5];
  const float* b1a = (const float*)d_in[6];
  const float* W1b = (const float*)d_in[7];
  const float* b1b = (const float*)d_in[8];
  const float* g1  = (const float*)d_in[9];
  const float* be1 = (const float*)d_in[10];
  const float* W2a = (const float*)d_in[11];
  const float* b2a = (const float*)d_in[12];
  const float* W2b = (const float*)d_in[13];
  const float* b2b = (const float*)d_in[14];
  const float* g2  = (const float*)d_in[15];
  const float* be2 = (const float*)d_in[16];

  int N = in_sizes[0] / D;        // 100000
  int E = in_sizes[1] / 2;        // 1600000
  int per = E / NG;               // 100000
  int tmul = N / NG;              // 6250

  float* ws = (float*)d_ws;
  size_t nd = (size_t)N * D;
  float* agg = ws;                 // aggregation output (both passes)
  float* h1  = ws + nd;            // post-MLP1 (BN'd in place)
  int*   col = (int*)(ws + 2 * nd);    // CSR src lists (N*SLOT ints)
  float* h2  = ws + 2 * nd;        // aliases col: col is dead before MLP2 writes
  float* stats = ws + 3 * nd;
  float* sum1 = stats +   0; float* sq1 = stats +  64;
  float* a1   = stats + 128; float* b1  = stats + 192;
  float* sum2 = stats + 256; float* sq2 = stats + 320;
  float* a2   = stats + 384; float* b2  = stats + 448;
  float* pool = stats + 512;            // 16*64
  float* cnt  = stats + 512 + NG * D;   // 16
  int*   fill = (int*)(stats + 512 + NG * D + NG);  // N ints (degree counts)

  // Zero stats block + fill[] in one memset (contiguous).
  hipMemsetAsync(stats, 0, (512 + NG * D + NG + N) * sizeof(float), stream);

  // Build CSR once; reused by both aggregation passes.
  build_csr_kernel<<<(E + 255) / 256, 256, 0, stream>>>(ei, fill, col, E, per, tmul);

  int gblocks = (N * 16 + 255) / 256;
  int mblocks = (N + 255) / 256;

  // Layer 1
  gather_agg_kernel<<<gblocks, 256, 0, stream>>>(x, col, fill, agg, N);
  mlp_kernel<32><<<mblocks, 256, 0, stream>>>(x, agg, W1a, b1a, W1b, b1b, h1, N);
  stats_kernel<<<256, 256, 0, stream>>>(h1, N, sum1, sq1);
  coeff_kernel<<<1, 64, 0, stream>>>(sum1, sq1, g1, be1, 1.f / N, a1, b1);
  bn_apply_kernel<<<(N * 16 + 255) / 256, 256, 0, stream>>>(h1, a1, b1, N * 16);

  // Layer 2 (gather reads col, then MLP2 overwrites that buffer as h2)
  gather_agg_kernel<<<gblocks, 256, 0, stream>>>(h1, col, fill, agg, N);
  mlp_kernel<64><<<mblocks, 256, 0, stream>>>(h1, agg, W2a, b2a, W2b, b2b, h2, N);
  stats_kernel<<<256, 256, 0, stream>>>(h2, N, sum2, sq2);
  coeff_kernel<<<1, 64, 0, stream>>>(sum2, sq2, g2, be2, 1.f / N, a2, b2);

  // Pool + fused BN2-affine + mean
  pool_kernel<<<256, 256, 0, stream>>>(h2, batch, N, pool, cnt);
  final_kernel<<<4, 256, 0, stream>>>(pool, cnt, a2, b2, (float*)d_out);
}

// Round 3
// 319.627 us; speedup vs baseline: 4.0876x; 1.2973x over previous
//
#include <hip/hip_runtime.h>

#define NG 16     // num_graphs (fixed by problem)
#define D 64      // feature width at every aggregation point
#define SLOT 64   // CSR slots per node; max in-degree lambda=8.5, P(>=64)~1e-30

// ---------------------------------------------------------------------------
// Build fixed-stride CSR by destination. One int atomic per VALID edge.
// ---------------------------------------------------------------------------
__global__ void build_csr_kernel(const int* __restrict__ ei,
                                 int* __restrict__ fill,
                                 int* __restrict__ col,
                                 int E, int per, int tmul) {
  int e = blockIdx.x * blockDim.x + threadIdx.x;
  if (e >= E) return;
  int src = ei[e];
  int dst = ei[E + e];
  int g = e / per;            // compiler magic-div
  int thr = g * tmul;
  if (src >= thr && dst >= thr) {
    int k = atomicAdd(&fill[dst], 1);
    if (k < SLOT) col[dst * SLOT + k] = src;   // clamp is paranoia-only
  }
}

// ---------------------------------------------------------------------------
// Fused layer: gather + (optional BN-fold of previous layer) + 2-linear MLP.
//   out[i] = relu( relu(in_i @ Wa + ba) @ Wb + bb )
//   in_i   = feat[i] + sum_{j in N(i)} feat[j]                 (FOLD_BN=false)
//   in_i   = a ⊙ (feat[i] + Σ feat[j]) + (1+deg_i) ⊙ b        (FOLD_BN=true,
//            a,b computed in-prologue from BN sum/sumsq/gamma/beta)
// Block = 256 threads = 16 nodes x 16 lanes. Lane q owns feature cols 4q..4q+3.
// All global loads/stores are 256B-coalesced per 16-lane group. MLP runs out
// of LDS (weights staged once per block; rows padded +4 -> conflict-free).
// Phases A->B are same-wave per node group, but __syncthreads for safety.
// ---------------------------------------------------------------------------
template <int MID, bool FOLD_BN>
__global__ __launch_bounds__(256) void fused_layer_kernel(
    const float* __restrict__ feat, const int* __restrict__ col,
    const int* __restrict__ deg,
    const float* __restrict__ bn_sum, const float* __restrict__ bn_sq,
    const float* __restrict__ bn_gamma, const float* __restrict__ bn_beta,
    float invN,
    const float* __restrict__ Wa, const float* __restrict__ ba,
    const float* __restrict__ Wb, const float* __restrict__ bb,
    float* __restrict__ out, int N) {
  constexpr int INP = D + 4;     // padded row stride (keeps float4 align, kills conflicts)
  constexpr int MIDP = MID + 4;
  __shared__ float s_in[16 * INP];
  __shared__ float s_mid[16 * MIDP];
  __shared__ float s_Wa[D * MID];
  __shared__ float s_Wb[MID * D];
  __shared__ float s_bna[D];
  __shared__ float s_bnb[D];

  int tid = threadIdx.x;

  // Stage weights (coalesced float4, once per block).
  {
    const float4* wa4 = (const float4*)Wa;
    const float4* wb4 = (const float4*)Wb;
    float4* sa4 = (float4*)s_Wa;
    float4* sb4 = (float4*)s_Wb;
    constexpr int NW = D * MID / 4;
#pragma unroll
    for (int i = tid; i < NW; i += 256) { sa4[i] = wa4[i]; sb4[i] = wb4[i]; }
  }
  if (FOLD_BN && tid < D) {
    float mean = bn_sum[tid] * invN;
    float var = bn_sq[tid] * invN - mean * mean;
    float av = bn_gamma[tid] * rsqrtf(var + 1e-5f);
    s_bna[tid] = av;
    s_bnb[tid] = bn_beta[tid] - mean * av;
  }
  __syncthreads();

  int n = tid >> 4;               // node slot within block
  int q = tid & 15;               // lane within group: cols 4q..4q+3
  int node = blockIdx.x * 16 + n;
  bool active = node < N;

  // ---- Phase A: gather + self + optional BN fold -> LDS row ----
  if (active) {
    int d = min(deg[node], SLOT);
    const int* cl = col + node * SLOT;
    float4 acc = *(const float4*)(feat + (size_t)node * D + q * 4);  // self term
    int j = 0;
    for (; j + 4 <= d; j += 4) {
      int4 s4 = *(const int4*)(cl + j);   // 4 independent gathers in flight
      float4 v0 = *(const float4*)(feat + (size_t)s4.x * D + q * 4);
      float4 v1 = *(const float4*)(feat + (size_t)s4.y * D + q * 4);
      float4 v2 = *(const float4*)(feat + (size_t)s4.z * D + q * 4);
      float4 v3 = *(const float4*)(feat + (size_t)s4.w * D + q * 4);
      acc.x += v0.x + v1.x + v2.x + v3.x;
      acc.y += v0.y + v1.y + v2.y + v3.y;
      acc.z += v0.z + v1.z + v2.z + v3.z;
      acc.w += v0.w + v1.w + v2.w + v3.w;
    }
    for (; j < d; j++) {
      int s = cl[j];
      float4 v = *(const float4*)(feat + (size_t)s * D + q * 4);
      acc.x += v.x; acc.y += v.y; acc.z += v.z; acc.w += v.w;
    }
    if (FOLD_BN) {
      float dp = (float)(d + 1);
      int c = q * 4;
      acc.x = s_bna[c + 0] * acc.x + dp * s_bnb[c + 0];
      acc.y = s_bna[c + 1] * acc.y + dp * s_bnb[c + 1];
      acc.z = s_bna[c + 2] * acc.z + dp * s_bnb[c + 2];
      acc.w = s_bna[c + 3] * acc.w + dp * s_bnb[c + 3];
    }
    *(float4*)&s_in[n * INP + q * 4] = acc;
  }
  __syncthreads();

  // ---- Phase B: per-node MLP out of LDS ----
  if (active) {
    constexpr int CPT = MID / 16;           // mid cols per thread (2 or 4)
    float acc[CPT];
#pragma unroll
    for (int u = 0; u < CPT; u++) acc[u] = ba[q * CPT + u];
#pragma unroll 4
    for (int j = 0; j < D; j++) {
      float v = s_in[n * INP + j];          // broadcast within group
#pragma unroll
      for (int u = 0; u < CPT; u++)
        acc[u] += v * s_Wa[j * MID + q * CPT + u];   // vectorizes to b64/b128
    }
#pragma unroll
    for (int u = 0; u < CPT; u++)
      s_mid[n * MIDP + q * CPT + u] = fmaxf(acc[u], 0.f);

    // stage 2 (same wave wrote s_mid; may-alias keeps order, barrier done above)
    float4 o = *(const float4*)(bb + q * 4);
#pragma unroll 4
    for (int k = 0; k < MID; k++) {
      float m = s_mid[n * MIDP + k];        // broadcast within group
      float4 w = *(const float4*)&s_Wb[k * D + q * 4];
      o.x += m * w.x; o.y += m * w.y; o.z += m * w.z; o.w += m * w.w;
    }
    o.x = fmaxf(o.x, 0.f); o.y = fmaxf(o.y, 0.f);
    o.z = fmaxf(o.z, 0.f); o.w = fmaxf(o.w, 0.f);
    *(float4*)(out + (size_t)node * D + q * 4) = o;   // coalesced
  }
}

// ---------------------------------------------------------------------------
// Column sums + sum-of-squares for BN training stats (reads h once).
// ---------------------------------------------------------------------------
__global__ void stats_kernel(const float* __restrict__ h, int N,
                             float* __restrict__ sum, float* __restrict__ sumsq) {
  __shared__ float ls[4 * D];
  __shared__ float lq[4 * D];
  int tid = threadIdx.x;
  int c = tid & (D - 1), w = tid >> 6;
  int chunk = (N + gridDim.x - 1) / gridDim.x;
  int r0 = blockIdx.x * chunk;
  int r1 = min(N, r0 + chunk);
  float s = 0.f, q = 0.f;
  for (int r = r0 + w; r < r1; r += 4) {
    float v = h[(size_t)r * D + c];
    s += v;
    q += v * v;
  }
  ls[w * D + c] = s;
  lq[w * D + c] = q;
  __syncthreads();
  if (tid < D) {
    float ts = ls[c] + ls[D + c] + ls[2 * D + c] + ls[3 * D + c];
    float tq = lq[c] + lq[D + c] + lq[2 * D + c] + lq[3 * D + c];
    atomicAdd(&sum[c], ts);
    atomicAdd(&sumsq[c], tq);
  }
}

// ---------------------------------------------------------------------------
// Fused global_mean_pool prep + BN2 stats: per-graph column sums & counts
// (run-length flush over sorted batch) + global column sum-of-squares.
// ---------------------------------------------------------------------------
__global__ void pool_stats_kernel(const float* __restrict__ h,
                                  const int* __restrict__ batch, int N,
                                  float* __restrict__ pool, float* __restrict__ cnt,
                                  float* __restrict__ sq) {
  __shared__ float lq[4 * D];
  int tid = threadIdx.x;
  int c = tid & (D - 1), w = tid >> 6;
  int chunk = (N + gridDim.x - 1) / gridDim.x;
  int r0 = blockIdx.x * chunk;
  int r1 = min(N, r0 + chunk);
  float acc = 0.f, lc = 0.f, qa = 0.f;
  int cur = -1;
  for (int r = r0 + w; r < r1; r += 4) {
    int g = batch[r];
    if (g != cur) {
      if (cur >= 0) {
        atomicAdd(&pool[cur * D + c], acc);
        if (c == 0) atomicAdd(&cnt[cur], lc);
      }
      cur = g; acc = 0.f; lc = 0.f;
    }
    float v = h[(size_t)r * D + c];
    acc += v; qa += v * v; lc += 1.f;
  }
  if (cur >= 0) {
    atomicAdd(&pool[cur * D + c], acc);
    if (c == 0) atomicAdd(&cnt[cur], lc);
  }
  lq[w * D + c] = qa;
  __syncthreads();
  if (tid < D)
    atomicAdd(&sq[c], lq[c] + lq[D + c] + lq[2 * D + c] + lq[3 * D + c]);
}

// ---------------------------------------------------------------------------
// Final: BN2 coeffs from (Σ_g pool, sq) + fused affine + mean divide.
// out[g,c] = (a2[c]*pool[g,c] + cnt[g]*b2[c]) / max(cnt[g],1)
// ---------------------------------------------------------------------------
__global__ void final_kernel(const float* __restrict__ pool,
                             const float* __restrict__ cnt,
                             const float* __restrict__ sq,
                             const float* __restrict__ gamma,
                             const float* __restrict__ beta,
                             float invN, float* __restrict__ out) {
  int c = threadIdx.x;   // 64 threads
  float s = 0.f;
#pragma unroll
  for (int g = 0; g < NG; g++) s += pool[g * D + c];
  float mean = s * invN;
  float var = sq[c] * invN - mean * mean;
  float a = gamma[c] * rsqrtf(var + 1e-5f);
  float b = beta[c] - mean * a;
#pragma unroll
  for (int g = 0; g < NG; g++) {
    float n = cnt[g];
    out[g * D + c] = (a * pool[g * D + c] + n * b) / fmaxf(n, 1.f);
  }
}

extern "C" void kernel_launch(void* const* d_in, const int* in_sizes, int n_in,
                              void* d_out, int out_size, void* d_ws, size_t ws_size,
                              hipStream_t stream) {
  const float* x   = (const float*)d_in[0];
  const int* ei    = (const int*)d_in[1];
  const int* batch = (const int*)d_in[2];
  const float* W1a = (const float*)d_in[5];
  const float* b1a = (const float*)d_in[6];
  const float* W1b = (const float*)d_in[7];
  const float* b1b = (const float*)d_in[8];
  const float* g1  = (const float*)d_in[9];
  const float* be1 = (const float*)d_in[10];
  const float* W2a = (const float*)d_in[11];
  const float* b2a = (const float*)d_in[12];
  const float* W2b = (const float*)d_in[13];
  const float* b2b = (const float*)d_in[14];
  const float* g2  = (const float*)d_in[15];
  const float* be2 = (const float*)d_in[16];

  int N = in_sizes[0] / D;        // 100000
  int E = in_sizes[1] / 2;        // 1600000
  int per = E / NG;               // 100000
  int tmul = N / NG;              // 6250
  float invN = 1.f / (float)N;

  float* ws = (float*)d_ws;
  size_t nd = (size_t)N * D;
  float* h1  = ws;                       // post-MLP1 (pre-BN; BN folded downstream)
  float* h2  = ws + nd;                  // post-MLP2 (pre-BN)
  int*   col = (int*)(ws + 2 * nd);      // CSR src lists (N*SLOT ints)
  float* stats = ws + 3 * nd;
  float* sum1 = stats;                   // 64
  float* sq1  = stats + 64;              // 64
  float* pool = stats + 128;             // 16*64
  float* cnt  = stats + 128 + NG * D;    // 16
  float* sq2  = stats + 144 + NG * D;    // 64
  int*   fill = (int*)(stats + 208 + NG * D);  // N ints (degree counts)

  // Zero the whole small-state region (stats + fill) in one shot.
  hipMemsetAsync(stats, 0, (208 + NG * D + N) * sizeof(float), stream);

  // CSR built once; reused by both layers.
  build_csr_kernel<<<(E + 255) / 256, 256, 0, stream>>>(ei, fill, col, E, per, tmul);

  int fblocks = (N + 15) / 16;

  // Layer 1: gather(x) + MLP1 -> h1 (pre-BN)
  fused_layer_kernel<32, false><<<fblocks, 256, 0, stream>>>(
      x, col, fill, nullptr, nullptr, nullptr, nullptr, invN,
      W1a, b1a, W1b, b1b, h1, N);
  stats_kernel<<<256, 256, 0, stream>>>(h1, N, sum1, sq1);

  // Layer 2: BN1 folded into gather input; -> h2 (pre-BN)
  fused_layer_kernel<64, true><<<fblocks, 256, 0, stream>>>(
      h1, col, fill, sum1, sq1, g1, be1, invN,
      W2a, b2a, W2b, b2b, h2, N);

  // Pool (per-graph sums+counts) + BN2 sumsq in one pass.
  pool_stats_kernel<<<256, 256, 0, stream>>>(h2, batch, N, pool, cnt, sq2);

  // BN2 coeffs + affine + mean.
  final_kernel<<<1, 64, 0, stream>>>(pool, cnt, sq2, g2, be2, invN, (float*)d_out);
}

// Round 4
// 306.614 us; speedup vs baseline: 4.2611x; 1.0424x over previous
//
#include <hip/hip_runtime.h>

#define NG 16     // num_graphs (fixed by problem)
#define D 64      // feature width at every aggregation point
#define SLOT 64   // CSR slots per node; in-degree ~ Poisson(<=16), P(>=64) negligible

// ---------------------------------------------------------------------------
// Build fixed-stride CSR by destination. One int atomic per VALID edge.
// ---------------------------------------------------------------------------
__global__ void build_csr_kernel(const int* __restrict__ ei,
                                 int* __restrict__ fill,
                                 int* __restrict__ col,
                                 int E, int per, int tmul) {
  int e = blockIdx.x * blockDim.x + threadIdx.x;
  if (e >= E) return;
  int src = ei[e];
  int dst = ei[E + e];
  int g = e / per;            // compiler magic-div
  int thr = g * tmul;
  if (src >= thr && dst >= thr) {
    int k = atomicAdd(&fill[dst], 1);
    if (k < SLOT) col[dst * SLOT + k] = src;   // clamp is paranoia-only
  }
}

// ---------------------------------------------------------------------------
// Fused layer: gather + (optional BN-fold of previous layer) + 2-linear MLP.
// Block = 512 threads, 64 nodes/block.
//  Phase A: 16 lanes/node (2 passes over 32 node slots), float4 gather -> LDS.
//  Phase B: register-tiled: thread (q, r2) computes nodes {2r2, 2r2+1} x
//           cols {q*C..}: one b64/b128 weight load serves 2 nodes, and the 4
//           r2-groups of a wave read the same weight address (broadcast).
//           Same node-pair stays in one wave across stage1/stage2 -> no extra
//           barrier after the post-gather __syncthreads.
// ---------------------------------------------------------------------------
template <int MID, bool FOLD_BN>
__global__ __launch_bounds__(512, 4) void fused_layer_kernel(
    const float* __restrict__ feat, const int* __restrict__ col,
    const int* __restrict__ deg,
    const float* __restrict__ bn_sum, const float* __restrict__ bn_sq,
    const float* __restrict__ bn_gamma, const float* __restrict__ bn_beta,
    float invN,
    const float* __restrict__ Wa, const float* __restrict__ ba,
    const float* __restrict__ Wb, const float* __restrict__ bb,
    float* __restrict__ out, int N) {
  constexpr int NPB = 64;        // nodes per block
  constexpr int INP = D + 4;     // padded strides (float4-aligned, conflict-free)
  constexpr int MIDP = MID + 4;
  __shared__ float s_in[NPB * INP];
  __shared__ float s_mid[NPB * MIDP];
  __shared__ float s_Wa[D * MID];
  __shared__ float s_Wb[MID * D];
  __shared__ float s_bna[D];
  __shared__ float s_bnb[D];

  int tid = threadIdx.x;

  // Stage weights (coalesced float4, once per block).
  {
    const float4* wa4 = (const float4*)Wa;
    const float4* wb4 = (const float4*)Wb;
    float4* sa4 = (float4*)s_Wa;
    float4* sb4 = (float4*)s_Wb;
    constexpr int NW = D * MID / 4;
#pragma unroll
    for (int i = tid; i < NW; i += 512) { sa4[i] = wa4[i]; sb4[i] = wb4[i]; }
  }
  if (FOLD_BN && tid < D) {
    float mean = bn_sum[tid] * invN;
    float var = bn_sq[tid] * invN - mean * mean;
    float av = bn_gamma[tid] * rsqrtf(var + 1e-5f);
    s_bna[tid] = av;
    s_bnb[tid] = bn_beta[tid] - mean * av;
  }
  __syncthreads();

  int q = tid & 15;               // lane within 16-group
  int base = blockIdx.x * NPB;

  // ---- Phase A: gather + self + optional BN fold -> LDS rows ----
  {
    int ns = tid >> 4;            // 0..31
#pragma unroll
    for (int pass = 0; pass < 2; pass++) {
      int slot = ns + 32 * pass;
      int node = base + slot;
      if (node < N) {
        int d = min(deg[node], SLOT);
        const int* cl = col + node * SLOT;
        float4 acc = *(const float4*)(feat + (size_t)node * D + q * 4);  // self
        int j = 0;
        for (; j + 4 <= d; j += 4) {
          int4 s4 = *(const int4*)(cl + j);
          float4 v0 = *(const float4*)(feat + (size_t)s4.x * D + q * 4);
          float4 v1 = *(const float4*)(feat + (size_t)s4.y * D + q * 4);
          float4 v2 = *(const float4*)(feat + (size_t)s4.z * D + q * 4);
          float4 v3 = *(const float4*)(feat + (size_t)s4.w * D + q * 4);
          acc.x += v0.x + v1.x + v2.x + v3.x;
          acc.y += v0.y + v1.y + v2.y + v3.y;
          acc.z += v0.z + v1.z + v2.z + v3.z;
          acc.w += v0.w + v1.w + v2.w + v3.w;
        }
        for (; j < d; j++) {
          int s = cl[j];
          float4 v = *(const float4*)(feat + (size_t)s * D + q * 4);
          acc.x += v.x; acc.y += v.y; acc.z += v.z; acc.w += v.w;
        }
        if (FOLD_BN) {
          float dp = (float)(d + 1);
          int c = q * 4;
          acc.x = s_bna[c + 0] * acc.x + dp * s_bnb[c + 0];
          acc.y = s_bna[c + 1] * acc.y + dp * s_bnb[c + 1];
          acc.z = s_bna[c + 2] * acc.z + dp * s_bnb[c + 2];
          acc.w = s_bna[c + 3] * acc.w + dp * s_bnb[c + 3];
        }
        *(float4*)&s_in[slot * INP + q * 4] = acc;
      }
    }
  }
  __syncthreads();

  // ---- Phase B: register-tiled MLP (2 nodes x C cols per thread) ----
  {
    int r2 = tid >> 4;            // 0..31 -> nodes 2r2, 2r2+1
    int n0 = 2 * r2, n1 = n0 + 1;
    constexpr int C1 = MID / 16;  // stage-1 cols per thread (2 or 4)

    // stage 1: mid = relu(in @ Wa + ba)
    float acc0[C1], acc1[C1];
#pragma unroll
    for (int u = 0; u < C1; u++) { acc0[u] = ba[q * C1 + u]; acc1[u] = acc0[u]; }
#pragma unroll 4
    for (int j = 0; j < D; j++) {
      float v0 = s_in[n0 * INP + j];
      float v1 = s_in[n1 * INP + j];
#pragma unroll
      for (int u = 0; u < C1; u++) {
        float w = s_Wa[j * MID + q * C1 + u];   // vectorizes to b64/b128
        acc0[u] += v0 * w;
        acc1[u] += v1 * w;
      }
    }
#pragma unroll
    for (int u = 0; u < C1; u++) {
      s_mid[n0 * MIDP + q * C1 + u] = fmaxf(acc0[u], 0.f);
      s_mid[n1 * MIDP + q * C1 + u] = fmaxf(acc1[u], 0.f);
    }
    // same-wave LDS write->read (node pair owned by the same wave)

    // stage 2: out = relu(mid @ Wb + bb), cols 4q..4q+3
    float4 o0 = *(const float4*)(bb + q * 4);
    float4 o1 = o0;
#pragma unroll 4
    for (int k = 0; k < MID; k++) {
      float m0 = s_mid[n0 * MIDP + k];
      float m1 = s_mid[n1 * MIDP + k];
      float4 w = *(const float4*)&s_Wb[k * D + q * 4];
      o0.x += m0 * w.x; o0.y += m0 * w.y; o0.z += m0 * w.z; o0.w += m0 * w.w;
      o1.x += m1 * w.x; o1.y += m1 * w.y; o1.z += m1 * w.z; o1.w += m1 * w.w;
    }
    int node0 = base + n0, node1 = base + n1;
    if (node0 < N) {
      o0.x = fmaxf(o0.x, 0.f); o0.y = fmaxf(o0.y, 0.f);
      o0.z = fmaxf(o0.z, 0.f); o0.w = fmaxf(o0.w, 0.f);
      *(float4*)(out + (size_t)node0 * D + q * 4) = o0;
    }
    if (node1 < N) {
      o1.x = fmaxf(o1.x, 0.f); o1.y = fmaxf(o1.y, 0.f);
      o1.z = fmaxf(o1.z, 0.f); o1.w = fmaxf(o1.w, 0.f);
      *(float4*)(out + (size_t)node1 * D + q * 4) = o1;
    }
  }
}

// ---------------------------------------------------------------------------
// Column sums + sum-of-squares for BN training stats (reads h once).
// ---------------------------------------------------------------------------
__global__ void stats_kernel(const float* __restrict__ h, int N,
                             float* __restrict__ sum, float* __restrict__ sumsq) {
  __shared__ float ls[4 * D];
  __shared__ float lq[4 * D];
  int tid = threadIdx.x;
  int c = tid & (D - 1), w = tid >> 6;
  int chunk = (N + gridDim.x - 1) / gridDim.x;
  int r0 = blockIdx.x * chunk;
  int r1 = min(N, r0 + chunk);
  float s = 0.f, q = 0.f;
  for (int r = r0 + w; r < r1; r += 4) {
    float v = h[(size_t)r * D + c];
    s += v;
    q += v * v;
  }
  ls[w * D + c] = s;
  lq[w * D + c] = q;
  __syncthreads();
  if (tid < D) {
    float ts = ls[c] + ls[D + c] + ls[2 * D + c] + ls[3 * D + c];
    float tq = lq[c] + lq[D + c] + lq[2 * D + c] + lq[3 * D + c];
    atomicAdd(&sum[c], ts);
    atomicAdd(&sumsq[c], tq);
  }
}

// ---------------------------------------------------------------------------
// Fused global_mean_pool prep + BN2 stats: per-graph column sums & counts
// (run-length flush over sorted batch) + global column sum-of-squares.
// ---------------------------------------------------------------------------
__global__ void pool_stats_kernel(const float* __restrict__ h,
                                  const int* __restrict__ batch, int N,
                                  float* __restrict__ pool, float* __restrict__ cnt,
                                  float* __restrict__ sq) {
  __shared__ float lq[4 * D];
  int tid = threadIdx.x;
  int c = tid & (D - 1), w = tid >> 6;
  int chunk = (N + gridDim.x - 1) / gridDim.x;
  int r0 = blockIdx.x * chunk;
  int r1 = min(N, r0 + chunk);
  float acc = 0.f, lc = 0.f, qa = 0.f;
  int cur = -1;
  for (int r = r0 + w; r < r1; r += 4) {
    int g = batch[r];
    if (g != cur) {
      if (cur >= 0) {
        atomicAdd(&pool[cur * D + c], acc);
        if (c == 0) atomicAdd(&cnt[cur], lc);
      }
      cur = g; acc = 0.f; lc = 0.f;
    }
    float v = h[(size_t)r * D + c];
    acc += v; qa += v * v; lc += 1.f;
  }
  if (cur >= 0) {
    atomicAdd(&pool[cur * D + c], acc);
    if (c == 0) atomicAdd(&cnt[cur], lc);
  }
  lq[w * D + c] = qa;
  __syncthreads();
  if (tid < D)
    atomicAdd(&sq[c], lq[c] + lq[D + c] + lq[2 * D + c] + lq[3 * D + c]);
}

// ---------------------------------------------------------------------------
// Final: BN2 coeffs from (Σ_g pool, sq) + fused affine + mean divide.
// ---------------------------------------------------------------------------
__global__ void final_kernel(const float* __restrict__ pool,
                             const float* __restrict__ cnt,
                             const float* __restrict__ sq,
                             const float* __restrict__ gamma,
                             const float* __restrict__ beta,
                             float invN, float* __restrict__ out) {
  int c = threadIdx.x;   // 64 threads
  float s = 0.f;
#pragma unroll
  for (int g = 0; g < NG; g++) s += pool[g * D + c];
  float mean = s * invN;
  float var = sq[c] * invN - mean * mean;
  float a = gamma[c] * rsqrtf(var + 1e-5f);
  float b = beta[c] - mean * a;
#pragma unroll
  for (int g = 0; g < NG; g++) {
    float n = cnt[g];
    out[g * D + c] = (a * pool[g * D + c] + n * b) / fmaxf(n, 1.f);
  }
}

extern "C" void kernel_launch(void* const* d_in, const int* in_sizes, int n_in,
                              void* d_out, int out_size, void* d_ws, size_t ws_size,
                              hipStream_t stream) {
  const float* x   = (const float*)d_in[0];
  const int* ei    = (const int*)d_in[1];
  const int* batch = (const int*)d_in[2];
  const float* W1a = (const float*)d_in[5];
  const float* b1a = (const float*)d_in[6];
  const float* W1b = (const float*)d_in[7];
  const float* b1b = (const float*)d_in[8];
  const float* g1  = (const float*)d_in[9];
  const float* be1 = (const float*)d_in[10];
  const float* W2a = (const float*)d_in[11];
  const float* b2a = (const float*)d_in[12];
  const float* W2b = (const float*)d_in[13];
  const float* b2b = (const float*)d_in[14];
  const float* g2  = (const float*)d_in[15];
  const float* be2 = (const float*)d_in[16];

  int N = in_sizes[0] / D;        // 100000
  int E = in_sizes[1] / 2;        // 1600000
  int per = E / NG;               // 100000
  int tmul = N / NG;              // 6250
  float invN = 1.f / (float)N;

  float* ws = (float*)d_ws;
  size_t nd = (size_t)N * D;
  float* h1  = ws;                       // post-MLP1 (pre-BN; BN folded downstream)
  float* h2  = ws + nd;                  // post-MLP2 (pre-BN)
  int*   col = (int*)(ws + 2 * nd);      // CSR src lists (N*SLOT ints)
  float* stats = ws + 3 * nd;
  float* sum1 = stats;                   // 64
  float* sq1  = stats + 64;              // 64
  float* pool = stats + 128;             // 16*64
  float* cnt  = stats + 128 + NG * D;    // 16
  float* sq2  = stats + 144 + NG * D;    // 64
  int*   fill = (int*)(stats + 208 + NG * D);  // N ints (degree counts)

  hipMemsetAsync(stats, 0, (208 + NG * D + N) * sizeof(float), stream);

  build_csr_kernel<<<(E + 255) / 256, 256, 0, stream>>>(ei, fill, col, E, per, tmul);

  int fblocks = (N + 63) / 64;

  // Layer 1: gather(x) + MLP1 -> h1 (pre-BN)
  fused_layer_kernel<32, false><<<fblocks, 512, 0, stream>>>(
      x, col, fill, nullptr, nullptr, nullptr, nullptr, invN,
      W1a, b1a, W1b, b1b, h1, N);
  stats_kernel<<<256, 256, 0, stream>>>(h1, N, sum1, sq1);

  // Layer 2: BN1 folded into gather input; -> h2 (pre-BN)
  fused_layer_kernel<64, true><<<fblocks, 512, 0, stream>>>(
      h1, col, fill, sum1, sq1, g1, be1, invN,
      W2a, b2a, W2b, b2b, h2, N);

  // Pool (per-graph sums+counts) + BN2 sumsq in one pass.
  pool_stats_kernel<<<256, 256, 0, stream>>>(h2, batch, N, pool, cnt, sq2);

  // BN2 coeffs + affine + mean.
  final_kernel<<<1, 64, 0, stream>>>(pool, cnt, sq2, g2, be2, invN, (float*)d_out);
}